// Round 1
// baseline (5819.119 us; speedup 1.0000x reference)
//
#include <hip/hip_runtime.h>
#include <cstddef>

// ---------- ordered-uint encoding for float atomicMax ----------
static __device__ __forceinline__ unsigned int fenc(float f) {
    unsigned int u = __float_as_uint(f);
    return (u & 0x80000000u) ? ~u : (u | 0x80000000u);
}
static __device__ __forceinline__ float fdec(unsigned int u) {
    return __uint_as_float((u & 0x80000000u) ? (u & 0x7fffffffu) : ~u);
}

// ---------- init agg to encoded floor (0 == below every real encode) ----------
__global__ void init_agg_kernel(unsigned int* __restrict__ aggu, int total) {
    int i = blockIdx.x * 256 + threadIdx.x;
    if (i < total) aggu[i] = 0u;
}

// ---------- edge message kernel: h2 = (relu([x_j, pos_j-pos_i] @ W1 + b1)) @ W2 + b2 ----------
// one thread per message (E edges + N self-loops); weights via wave-uniform scalar loads
#define TPB_E 256
__global__ __launch_bounds__(TPB_E, 2) void edge_msg_kernel(
    const float* __restrict__ x, const float* __restrict__ pos,
    const int* __restrict__ ei, int E, int Nn,
    const float* __restrict__ W1, const float* __restrict__ b1,
    const float* __restrict__ W2, const float* __restrict__ b2,
    unsigned int* __restrict__ aggu)
{
    int m = blockIdx.x * TPB_E + threadIdx.x;
    int M = E + Nn;
    if (m >= M) return;

    int src, dst;
    float p0 = 0.f, p1 = 0.f, p2 = 0.f;
    if (m < E) {
        src = ei[m];
        dst = ei[E + m];
        p0 = pos[src * 3 + 0] - pos[dst * 3 + 0];
        p1 = pos[src * 3 + 1] - pos[dst * 3 + 1];
        p2 = pos[src * 3 + 2] - pos[dst * 3 + 2];
    } else {
        src = m - E;
        dst = src;
    }
    float x0 = x[src * 3 + 0], x1 = x[src * 3 + 1], x2 = x[src * 3 + 2];

    // layer 1: 6 -> 64, relu
    float h[64];
#pragma unroll
    for (int c = 0; c < 64; ++c) {
        float t = b1[c];
        t = fmaf(x0, W1[0 * 64 + c], t);
        t = fmaf(x1, W1[1 * 64 + c], t);
        t = fmaf(x2, W1[2 * 64 + c], t);
        t = fmaf(p0, W1[3 * 64 + c], t);
        t = fmaf(p1, W1[4 * 64 + c], t);
        t = fmaf(p2, W1[5 * 64 + c], t);
        h[c] = fmaxf(t, 0.f);
    }

    // layer 2: 64 -> 64 (no relu)
    float a[64];
#pragma unroll
    for (int c = 0; c < 64; ++c) a[c] = b2[c];
#pragma unroll
    for (int j = 0; j < 64; ++j) {
        float hj = h[j];
#pragma unroll
        for (int c = 0; c < 64; ++c) a[c] = fmaf(hj, W2[j * 64 + c], a[c]);
    }

    // max-aggregate: load-filter then atomicMax (monotonic => stale reads safe)
    unsigned int* ap = aggu + (size_t)dst * 64;
    const uint4* cp = (const uint4*)ap;
#pragma unroll
    for (int q = 0; q < 16; ++q) {
        uint4 cu = cp[q];
        unsigned int e0 = fenc(a[q * 4 + 0]);
        unsigned int e1 = fenc(a[q * 4 + 1]);
        unsigned int e2 = fenc(a[q * 4 + 2]);
        unsigned int e3 = fenc(a[q * 4 + 3]);
        if (e0 > cu.x) atomicMax(ap + q * 4 + 0, e0);
        if (e1 > cu.y) atomicMax(ap + q * 4 + 1, e1);
        if (e2 > cu.z) atomicMax(ap + q * 4 + 2, e2);
        if (e3 > cu.w) atomicMax(ap + q * 4 + 3, e3);
    }
}

// ---------- fused node kernel: agg -> g1(128) -> g2(1024) -> g3(64) -> fc(40) -> log_softmax ----------
// one thread per node; weights via wave-uniform scalar loads (amortized 64x per wave)
#define TPB_N 64
__global__ __launch_bounds__(TPB_N, 1) void node_kernel(
    const unsigned int* __restrict__ aggu,
    const float* __restrict__ W3, const float* __restrict__ b3,
    const float* __restrict__ W4, const float* __restrict__ b4,
    const float* __restrict__ W5, const float* __restrict__ b5,
    const float* __restrict__ Wf, const float* __restrict__ bf,
    float* __restrict__ out, int Nn)
{
    __shared__ float scratch[TPB_N][129];  // stride 129: bank=(tid+j)%32, conflict-free
    int n = blockIdx.x * TPB_N + threadIdx.x;
    if (n >= Nn) return;
    int tid = threadIdx.x;

    // ---- g1 = relu(agg @ W3 + b3) : 64 -> 128 ----
    float g1[128];
#pragma unroll
    for (int c = 0; c < 128; ++c) g1[c] = b3[c];
    const unsigned int* arow = aggu + (size_t)n * 64;
#pragma unroll 4
    for (int j = 0; j < 64; ++j) {
        float av = fdec(arow[j]);
#pragma unroll
        for (int c = 0; c < 128; ++c) g1[c] = fmaf(av, W3[j * 128 + c], g1[c]);
    }
#pragma unroll
    for (int c = 0; c < 128; ++c) scratch[tid][c] = fmaxf(g1[c], 0.f);

    // ---- g3 = relu(g1 @ W4 + b4) @ W5 + b5, fused over k in chunks of 8 ----
    float g3[64];
#pragma unroll
    for (int c = 0; c < 64; ++c) g3[c] = b5[c];

    for (int kc = 0; kc < 128; ++kc) {  // 128 chunks x 8 channels of g2
        float t[8];
#pragma unroll
        for (int q = 0; q < 8; ++q) t[q] = b4[kc * 8 + q];
#pragma unroll 4
        for (int j = 0; j < 128; ++j) {
            float gj = scratch[tid][j];
            const float* w = W4 + j * 1024 + kc * 8;
#pragma unroll
            for (int q = 0; q < 8; ++q) t[q] = fmaf(gj, w[q], t[q]);
        }
#pragma unroll
        for (int q = 0; q < 8; ++q) {
            float g2 = fmaxf(t[q], 0.f);
            const float* w5 = W5 + (kc * 8 + q) * 64;
#pragma unroll
            for (int c = 0; c < 64; ++c) g3[c] = fmaf(g2, w5[c], g3[c]);
        }
    }

    // ---- out = relu(g3) @ Wf + bf, then log_softmax ----
#pragma unroll
    for (int c = 0; c < 64; ++c) scratch[tid][c] = fmaxf(g3[c], 0.f);
    float o[40];
#pragma unroll
    for (int c = 0; c < 40; ++c) o[c] = bf[c];
#pragma unroll 4
    for (int j = 0; j < 64; ++j) {
        float aj = scratch[tid][j];
#pragma unroll
        for (int c = 0; c < 40; ++c) o[c] = fmaf(aj, Wf[j * 40 + c], o[c]);
    }
    float mx = o[0];
#pragma unroll
    for (int c = 1; c < 40; ++c) mx = fmaxf(mx, o[c]);
    float s = 0.f;
#pragma unroll
    for (int c = 0; c < 40; ++c) s += expf(o[c] - mx);
    float ls = logf(s);
    float* op = out + (size_t)n * 40;
#pragma unroll
    for (int c = 0; c < 40; ++c) op[c] = o[c] - mx - ls;
}

extern "C" void kernel_launch(void* const* d_in, const int* in_sizes, int n_in,
                              void* d_out, int out_size, void* d_ws, size_t ws_size,
                              hipStream_t stream) {
    const float* x   = (const float*)d_in[0];
    const float* pos = (const float*)d_in[1];
    const int*   ei  = (const int*)d_in[2];
    const float* W1  = (const float*)d_in[3];
    const float* b1  = (const float*)d_in[4];
    const float* W2  = (const float*)d_in[5];
    const float* b2  = (const float*)d_in[6];
    const float* W3  = (const float*)d_in[7];
    const float* b3  = (const float*)d_in[8];
    const float* W4  = (const float*)d_in[9];
    const float* b4  = (const float*)d_in[10];
    const float* W5  = (const float*)d_in[11];
    const float* b5  = (const float*)d_in[12];
    const float* Wf  = (const float*)d_in[13];
    const float* bf  = (const float*)d_in[14];
    float* out = (float*)d_out;

    int Nn = in_sizes[0] / 3;       // 50000
    int E  = in_sizes[2] / 2;       // 1600000

    unsigned int* aggu = (unsigned int*)d_ws;  // N x 64 encoded-max buffer (12.8 MB)

    int aggTotal = Nn * 64;
    init_agg_kernel<<<(aggTotal + 255) / 256, 256, 0, stream>>>(aggu, aggTotal);

    int M = E + Nn;
    edge_msg_kernel<<<(M + TPB_E - 1) / TPB_E, TPB_E, 0, stream>>>(
        x, pos, ei, E, Nn, W1, b1, W2, b2, aggu);

    node_kernel<<<(Nn + TPB_N - 1) / TPB_N, TPB_N, 0, stream>>>(
        aggu, W3, b3, W4, b4, W5, b5, Wf, bf, out, Nn);
}

// Round 2
// 3623.871 us; speedup vs baseline: 1.6058x; 1.6058x over previous
//
#include <hip/hip_runtime.h>
#include <cstddef>

// ---------- ordered-uint encoding for float atomicMax ----------
static __device__ __forceinline__ unsigned int fenc(float f) {
    unsigned int u = __float_as_uint(f);
    return (u & 0x80000000u) ? ~u : (u | 0x80000000u);
}
static __device__ __forceinline__ float fdec(unsigned int u) {
    return __uint_as_float((u & 0x80000000u) ? (u & 0x7fffffffu) : ~u);
}

// ---------- init agg to encoded floor (0 == below every real encode) ----------
__global__ void init_agg_kernel(unsigned int* __restrict__ aggu, int total) {
    int i = blockIdx.x * 256 + threadIdx.x;
    if (i < total) aggu[i] = 0u;
}

// ---------- edge message kernel ----------
// one thread per message (E edges + N self-loops).
// Register-pressure-shaped: h[64] stays live; output computed in 4 chunks of 16
// (peak live ~90 floats -> no scratch spill; R1's monolithic a[64]+h[64] spilled
// at VGPR_Count=76 causing 5.26 GB scratch traffic).
#define TPB_E 256
__global__ __launch_bounds__(TPB_E, 3) void edge_msg_kernel(
    const float* __restrict__ x, const float* __restrict__ pos,
    const int* __restrict__ ei, int E, int Nn,
    const float* __restrict__ W1, const float* __restrict__ b1,
    const float* __restrict__ W2, const float* __restrict__ b2,
    unsigned int* __restrict__ aggu)
{
    int m = blockIdx.x * TPB_E + threadIdx.x;
    int M = E + Nn;
    if (m >= M) return;

    int src, dst;
    float p0 = 0.f, p1 = 0.f, p2 = 0.f;
    if (m < E) {
        src = ei[m];
        dst = ei[E + m];
        p0 = pos[src * 3 + 0] - pos[dst * 3 + 0];
        p1 = pos[src * 3 + 1] - pos[dst * 3 + 1];
        p2 = pos[src * 3 + 2] - pos[dst * 3 + 2];
    } else {
        src = m - E;
        dst = src;
    }
    float x0 = x[src * 3 + 0], x1 = x[src * 3 + 1], x2 = x[src * 3 + 2];

    // layer 1: 6 -> 64, relu (h stays live across the whole layer-2 phase)
    float h[64];
#pragma unroll
    for (int c = 0; c < 64; ++c) {
        float t = b1[c];
        t = fmaf(x0, W1[0 * 64 + c], t);
        t = fmaf(x1, W1[1 * 64 + c], t);
        t = fmaf(x2, W1[2 * 64 + c], t);
        t = fmaf(p0, W1[3 * 64 + c], t);
        t = fmaf(p1, W1[4 * 64 + c], t);
        t = fmaf(p2, W1[5 * 64 + c], t);
        h[c] = fmaxf(t, 0.f);
    }

    // layer 2 + aggregation, 4 chunks of 16 output channels
    unsigned int* ap = aggu + (size_t)dst * 64;
#pragma unroll
    for (int ch = 0; ch < 4; ++ch) {
        float acc[16];
#pragma unroll
        for (int q = 0; q < 16; ++q) acc[q] = b2[ch * 16 + q];
#pragma unroll
        for (int j = 0; j < 64; ++j) {
            float hj = h[j];
            const float* w = W2 + j * 64 + ch * 16;
#pragma unroll
            for (int q = 0; q < 16; ++q) acc[q] = fmaf(hj, w[q], acc[q]);
        }
        // load-filter then atomicMax (cell value monotonic => stale reads safe)
        const uint4* cp = (const uint4*)(ap + ch * 16);
#pragma unroll
        for (int v = 0; v < 4; ++v) {
            uint4 cu = cp[v];
            unsigned int e0 = fenc(acc[v * 4 + 0]);
            unsigned int e1 = fenc(acc[v * 4 + 1]);
            unsigned int e2 = fenc(acc[v * 4 + 2]);
            unsigned int e3 = fenc(acc[v * 4 + 3]);
            unsigned int* b = ap + ch * 16 + v * 4;
            if (e0 > cu.x) atomicMax(b + 0, e0);
            if (e1 > cu.y) atomicMax(b + 1, e1);
            if (e2 > cu.z) atomicMax(b + 2, e2);
            if (e3 > cu.w) atomicMax(b + 3, e3);
        }
    }
}

// ---------- fused node kernel: agg -> g1(128) -> g2(1024) -> g3(64) -> fc(40) -> log_softmax ----------
// one thread per node; weights via wave-uniform scalar loads (amortized 64x per wave).
// Register-shaped: agg row (64 regs) + g1 chunk (32) in phase 1; g3[64]+t[8] in phase 2.
#define TPB_N 64
__global__ __launch_bounds__(TPB_N, 2) void node_kernel(
    const unsigned int* __restrict__ aggu,
    const float* __restrict__ W3, const float* __restrict__ b3,
    const float* __restrict__ W4, const float* __restrict__ b4,
    const float* __restrict__ W5, const float* __restrict__ b5,
    const float* __restrict__ Wf, const float* __restrict__ bf,
    float* __restrict__ out, int Nn)
{
    __shared__ float scratch[TPB_N][129];  // stride 129: bank=(tid+j)%32, free 2-way
    int n = blockIdx.x * TPB_N + threadIdx.x;
    if (n >= Nn) return;
    int tid = threadIdx.x;

    // decode agg row into registers
    float ar[64];
    const unsigned int* arow = aggu + (size_t)n * 64;
#pragma unroll
    for (int j = 0; j < 64; ++j) ar[j] = fdec(arow[j]);

    // ---- g1 = relu(agg @ W3 + b3) : 64 -> 128, in 4 chunks of 32, straight to LDS ----
#pragma unroll
    for (int ch = 0; ch < 4; ++ch) {
        float g[32];
#pragma unroll
        for (int q = 0; q < 32; ++q) g[q] = b3[ch * 32 + q];
#pragma unroll
        for (int j = 0; j < 64; ++j) {
            float av = ar[j];
            const float* w = W3 + j * 128 + ch * 32;
#pragma unroll
            for (int q = 0; q < 32; ++q) g[q] = fmaf(av, w[q], g[q]);
        }
#pragma unroll
        for (int q = 0; q < 32; ++q) scratch[tid][ch * 32 + q] = fmaxf(g[q], 0.f);
    }

    // ---- g3 = relu(g1 @ W4 + b4) @ W5 + b5, fused over k in chunks of 8 ----
    float g3[64];
#pragma unroll
    for (int c = 0; c < 64; ++c) g3[c] = b5[c];

    for (int kc = 0; kc < 128; ++kc) {  // 128 chunks x 8 channels of g2
        float t[8];
#pragma unroll
        for (int q = 0; q < 8; ++q) t[q] = b4[kc * 8 + q];
#pragma unroll 4
        for (int j = 0; j < 128; ++j) {
            float gj = scratch[tid][j];
            const float* w = W4 + j * 1024 + kc * 8;
#pragma unroll
            for (int q = 0; q < 8; ++q) t[q] = fmaf(gj, w[q], t[q]);
        }
#pragma unroll
        for (int q = 0; q < 8; ++q) {
            float g2 = fmaxf(t[q], 0.f);
            const float* w5 = W5 + (kc * 8 + q) * 64;
#pragma unroll
            for (int c = 0; c < 64; ++c) g3[c] = fmaf(g2, w5[c], g3[c]);
        }
    }

    // ---- out = relu(g3) @ Wf + bf, then log_softmax ----
#pragma unroll
    for (int c = 0; c < 64; ++c) scratch[tid][c] = fmaxf(g3[c], 0.f);
    float o[40];
#pragma unroll
    for (int c = 0; c < 40; ++c) o[c] = bf[c];
#pragma unroll 4
    for (int j = 0; j < 64; ++j) {
        float aj = scratch[tid][j];
#pragma unroll
        for (int c = 0; c < 40; ++c) o[c] = fmaf(aj, Wf[j * 40 + c], o[c]);
    }
    float mx = o[0];
#pragma unroll
    for (int c = 1; c < 40; ++c) mx = fmaxf(mx, o[c]);
    float s = 0.f;
#pragma unroll
    for (int c = 0; c < 40; ++c) s += expf(o[c] - mx);
    float ls = logf(s);
    float* op = out + (size_t)n * 40;
#pragma unroll
    for (int c = 0; c < 40; ++c) op[c] = o[c] - mx - ls;
}

extern "C" void kernel_launch(void* const* d_in, const int* in_sizes, int n_in,
                              void* d_out, int out_size, void* d_ws, size_t ws_size,
                              hipStream_t stream) {
    const float* x   = (const float*)d_in[0];
    const float* pos = (const float*)d_in[1];
    const int*   ei  = (const int*)d_in[2];
    const float* W1  = (const float*)d_in[3];
    const float* b1  = (const float*)d_in[4];
    const float* W2  = (const float*)d_in[5];
    const float* b2  = (const float*)d_in[6];
    const float* W3  = (const float*)d_in[7];
    const float* b3  = (const float*)d_in[8];
    const float* W4  = (const float*)d_in[9];
    const float* b4  = (const float*)d_in[10];
    const float* W5  = (const float*)d_in[11];
    const float* b5  = (const float*)d_in[12];
    const float* Wf  = (const float*)d_in[13];
    const float* bf  = (const float*)d_in[14];
    float* out = (float*)d_out;

    int Nn = in_sizes[0] / 3;       // 50000
    int E  = in_sizes[2] / 2;       // 1600000

    unsigned int* aggu = (unsigned int*)d_ws;  // N x 64 encoded-max buffer (12.8 MB)

    int aggTotal = Nn * 64;
    init_agg_kernel<<<(aggTotal + 255) / 256, 256, 0, stream>>>(aggu, aggTotal);

    int M = E + Nn;
    edge_msg_kernel<<<(M + TPB_E - 1) / TPB_E, TPB_E, 0, stream>>>(
        x, pos, ei, E, Nn, W1, b1, W2, b2, aggu);

    node_kernel<<<(Nn + TPB_N - 1) / TPB_N, TPB_N, 0, stream>>>(
        aggu, W3, b3, W4, b4, W5, b5, Wf, bf, out, Nn);
}